// Round 1
// baseline (3916.941 us; speedup 1.0000x reference)
//
#include <hip/hip_runtime.h>

#define ENC_NODES 8

// ---------------- Encoder: 5 linears + lrelu + concat -> [N,128] ----------------
__global__ __launch_bounds__(128) void encoder_kernel(
    const float* __restrict__ des, const float* __restrict__ tweet,
    const float* __restrict__ nump, const float* __restrict__ catp,
    const float* __restrict__ nf,
    const float* __restrict__ Wd, const float* __restrict__ bd,
    const float* __restrict__ Wt, const float* __restrict__ bt,
    const float* __restrict__ Wn, const float* __restrict__ bn,
    const float* __restrict__ Wc, const float* __restrict__ bc,
    const float* __restrict__ Ww, const float* __restrict__ bw,
    float* __restrict__ out, int n)
{
    __shared__ float ld[ENC_NODES * 768];
    __shared__ float lt[ENC_NODES * 768];
    int n0 = blockIdx.x * ENC_NODES;
    // cooperative load of 8 des rows + 8 tweet rows (float4, coalesced)
    const float4* d4 = (const float4*)(des + (size_t)n0 * 768);
    const float4* t4 = (const float4*)(tweet + (size_t)n0 * 768);
    float4* ld4 = (float4*)ld;
    float4* lt4 = (float4*)lt;
    for (int i = threadIdx.x; i < ENC_NODES * 192; i += 128) { ld4[i] = d4[i]; lt4[i] = t4[i]; }
    __syncthreads();

    int j = threadIdx.x;  // output column 0..127
    float acc[ENC_NODES];
#pragma unroll
    for (int m = 0; m < ENC_NODES; m++) acc[m] = 0.f;
    float bb = 0.f;

    if (j < 64) {
        // wave 0: the two 768-length dots (des cols 0..27, tweet cols 28..63)
        const float* wp; int stride; const float* xb;
        if (j < 28) { wp = Wd + j;        stride = 28; xb = ld; bb = bd[j]; }
        else        { wp = Wt + (j - 28); stride = 36; xb = lt; bb = bt[j - 28]; }
        for (int k = 0; k < 768; k++) {
            float w = wp[(size_t)k * stride];
#pragma unroll
            for (int m = 0; m < ENC_NODES; m++) acc[m] += xb[m * 768 + k] * w;
        }
    } else if (j < 76) {
        int c = j - 64; bb = bn[c];
        for (int k = 0; k < 7; k++) {
            float w = Wn[k * 12 + c];
#pragma unroll
            for (int m = 0; m < ENC_NODES; m++) acc[m] += nump[(size_t)(n0 + m) * 7 + k] * w;
        }
    } else if (j < 116) {
        int c = j - 76; bb = bc[c];
        for (int k = 0; k < 11; k++) {
            float w = Wc[k * 40 + c];
#pragma unroll
            for (int m = 0; m < ENC_NODES; m++) acc[m] += catp[(size_t)(n0 + m) * 11 + k] * w;
        }
    } else {
        int c = j - 116; bb = bw[c];
        float w = Ww[c];
#pragma unroll
        for (int m = 0; m < ENC_NODES; m++) acc[m] += nf[n0 + m] * w;
    }

#pragma unroll
    for (int m = 0; m < ENC_NODES; m++) {
        float v = acc[m] + bb;
        v = v > 0.f ? v : 0.01f * v;  // leaky relu 0.01
        out[(size_t)(n0 + m) * 128 + j] = v;
    }
}

// ---------------- Dense [N,128] @ [128,128] (+bias, +optional lrelu) ----------------
__global__ __launch_bounds__(256) void dense128_kernel(
    const float* __restrict__ X, const float* __restrict__ W,
    const float* __restrict__ bias, float* __restrict__ Y,
    int nrows, int relu)
{
    __shared__ float Wl[128 * 128];  // 64 KB
    __shared__ float Xl[32 * 128];   // 16 KB
    {
        const float4* W4 = (const float4*)W;
        float4* Wl4 = (float4*)Wl;
        for (int i = threadIdx.x; i < 4096; i += 256) Wl4[i] = W4[i];
    }
    int cg = threadIdx.x & 31;   // column group: cols cg*4 .. cg*4+3
    int rg = threadIdx.x >> 5;   // row group:    rows rg*4 .. rg*4+3 (within 32-row tile)
    int nchunks = (nrows + 31) >> 5;
    for (int chunk = blockIdx.x; chunk < nchunks; chunk += gridDim.x) {
        int base = chunk * 32;
        __syncthreads();  // previous iteration's Xl reads done (also orders W load on iter 0)
        {
            const float4* X4 = (const float4*)(X + (size_t)base * 128);
            float4* Xl4 = (float4*)Xl;
            for (int i = threadIdx.x; i < 1024; i += 256) Xl4[i] = X4[i];
        }
        __syncthreads();
        float acc[4][4];
#pragma unroll
        for (int a = 0; a < 4; a++)
#pragma unroll
            for (int b = 0; b < 4; b++) acc[a][b] = 0.f;
#pragma unroll 4
        for (int k = 0; k < 128; k++) {
            float4 w = ((const float4*)(Wl + k * 128))[cg];
#pragma unroll
            for (int rr = 0; rr < 4; rr++) {
                float xv = Xl[(rg * 4 + rr) * 128 + k];
                acc[rr][0] += xv * w.x;
                acc[rr][1] += xv * w.y;
                acc[rr][2] += xv * w.z;
                acc[rr][3] += xv * w.w;
            }
        }
        float4 bv;
        if (bias) bv = ((const float4*)bias)[cg];
        else { bv.x = bv.y = bv.z = bv.w = 0.f; }
#pragma unroll
        for (int rr = 0; rr < 4; rr++) {
            float4 o;
            o.x = acc[rr][0] + bv.x;
            o.y = acc[rr][1] + bv.y;
            o.z = acc[rr][2] + bv.z;
            o.w = acc[rr][3] + bv.w;
            if (relu) {
                o.x = o.x > 0.f ? o.x : 0.01f * o.x;
                o.y = o.y > 0.f ? o.y : 0.01f * o.y;
                o.z = o.z > 0.f ? o.z : 0.01f * o.z;
                o.w = o.w > 0.f ? o.w : 0.01f * o.w;
            }
            ((float4*)(Y + (size_t)(base + rg * 4 + rr) * 128))[cg] = o;
        }
    }
}

// ---------------- Degree count + reciprocal ----------------
__global__ void count_kernel(const int* __restrict__ ei, const int* __restrict__ et,
                             float* __restrict__ cnt, int E, int N)
{
    int e = blockIdx.x * 256 + threadIdx.x;
    if (e < E) atomicAdd(&cnt[(size_t)et[e] * N + ei[E + e]], 1.0f);
}

__global__ void inv_kernel(float* __restrict__ p, int n)
{
    int i = blockIdx.x * 256 + threadIdx.x;
    if (i < n) p[i] = 1.0f / fmaxf(p[i], 1.0f);
}

// ---------------- Edge scatter: out[dst] += xr[src] * inv_deg[dst] ----------------
__global__ __launch_bounds__(256) void scatter_kernel(
    const float* __restrict__ xr, const int* __restrict__ ei,
    const int* __restrict__ et, const float* __restrict__ inv,
    float* __restrict__ out, int rel, int E)
{
    int e = blockIdx.x * 2 + (threadIdx.x >> 7);
    if (e >= E || et[e] != rel) return;
    int j = threadIdx.x & 127;
    int s = ei[e], d = ei[E + e];
    float v = xr[(size_t)s * 128 + j] * inv[d];
    atomicAdd(&out[(size_t)d * 128 + j], v);
}

// ---------------- Head: out = y @ W_o2 + b_o2, wave per node ----------------
__global__ __launch_bounds__(256) void head_kernel(
    const float* __restrict__ y, const float* __restrict__ W2,
    const float* __restrict__ b2, float* __restrict__ out, int n)
{
    int node = blockIdx.x * 4 + (threadIdx.x >> 6);
    if (node >= n) return;
    int lane = threadIdx.x & 63;
    float x0 = y[(size_t)node * 128 + lane];
    float x1 = y[(size_t)node * 128 + 64 + lane];
    float s0 = x0 * W2[lane * 2]     + x1 * W2[(lane + 64) * 2];
    float s1 = x0 * W2[lane * 2 + 1] + x1 * W2[(lane + 64) * 2 + 1];
#pragma unroll
    for (int off = 32; off > 0; off >>= 1) {
        s0 += __shfl_down(s0, off);
        s1 += __shfl_down(s1, off);
    }
    if (lane == 0) {
        out[(size_t)node * 2]     = s0 + b2[0];
        out[(size_t)node * 2 + 1] = s1 + b2[1];
    }
}

extern "C" void kernel_launch(void* const* d_in, const int* in_sizes, int n_in,
                              void* d_out, int out_size, void* d_ws, size_t ws_size,
                              hipStream_t stream)
{
    const float* des   = (const float*)d_in[0];
    const float* tweet = (const float*)d_in[1];
    const float* nump  = (const float*)d_in[2];
    const float* catp  = (const float*)d_in[3];
    const float* nf    = (const float*)d_in[4];
    const int*   ei    = (const int*)d_in[5];
    const int*   et    = (const int*)d_in[6];
    const float* Wd  = (const float*)d_in[7],  *bd  = (const float*)d_in[8];
    const float* Wt  = (const float*)d_in[9],  *bt  = (const float*)d_in[10];
    const float* Wn  = (const float*)d_in[11], *bn  = (const float*)d_in[12];
    const float* Wc  = (const float*)d_in[13], *bc  = (const float*)d_in[14];
    const float* Ww  = (const float*)d_in[15], *bw  = (const float*)d_in[16];
    const float* Win = (const float*)d_in[17], *bin = (const float*)d_in[18];
    const float* Wroot = (const float*)d_in[19];
    const float* Wrel  = (const float*)d_in[20];
    const float* brg   = (const float*)d_in[21];
    const float* Wo1 = (const float*)d_in[22], *bo1 = (const float*)d_in[23];
    const float* Wo2 = (const float*)d_in[24], *bo2 = (const float*)d_in[25];

    int N = in_sizes[0] / 768;   // 100000
    int E = in_sizes[6];         // 600000

    // workspace: P, Q, R = [N,128] f32 each; inv = [2,N] f32. Total 154.4 MB.
    float* P   = (float*)d_ws;
    float* Q   = P + (size_t)N * 128;
    float* R   = Q + (size_t)N * 128;
    float* inv = R + (size_t)N * 128;

    hipMemsetAsync(inv, 0, (size_t)2 * N * sizeof(float), stream);

    encoder_kernel<<<(N + ENC_NODES - 1) / ENC_NODES, 128, 0, stream>>>(
        des, tweet, nump, catp, nf, Wd, bd, Wt, bt, Wn, bn, Wc, bc, Ww, bw, P, N);

    count_kernel<<<(E + 255) / 256, 256, 0, stream>>>(ei, et, inv, E, N);
    inv_kernel<<<(2 * N + 255) / 256, 256, 0, stream>>>(inv, 2 * N);

    int nchunks = (N + 31) / 32;
    // x = lrelu(xcat @ W_in + b_in)
    dense128_kernel<<<nchunks, 256, 0, stream>>>(P, Win, bin, Q, N, 1);

    float* x = Q;
    float* y = P;
    for (int i = 0; i < 4; i++) {
        // h = x @ W_root[i] + b_rgcn[i]  (no activation between RGCN layers)
        dense128_kernel<<<nchunks, 256, 0, stream>>>(
            x, Wroot + (size_t)i * 16384, brg + (size_t)i * 128, y, N, 0);
        for (int r = 0; r < 2; r++) {
            // xr = x @ W_rel[i][r]
            dense128_kernel<<<nchunks, 256, 0, stream>>>(
                x, Wrel + (size_t)(i * 2 + r) * 16384, nullptr, R, N, 0);
            // y[dst] += xr[src] * (1/deg_r(dst))   — mean folded into scatter
            scatter_kernel<<<(E + 1) / 2, 256, 0, stream>>>(
                R, ei, et, inv + (size_t)r * N, y, r, E);
        }
        float* t = x; x = y; y = t;
    }

    // x = lrelu(x @ W_o1 + b_o1)
    dense128_kernel<<<nchunks, 256, 0, stream>>>(x, Wo1, bo1, y, N, 1);
    // out = x @ W_o2 + b_o2
    head_kernel<<<(N + 3) / 4, 256, 0, stream>>>(y, Wo2, bo2, (float*)d_out, N);
}

// Round 2
// 2172.338 us; speedup vs baseline: 1.8031x; 1.8031x over previous
//
#include <hip/hip_runtime.h>

// ================= Encoder big: cols 0..63 = lrelu([des|tweet] @ [Wd|Wt] + b) =================
// Tiled GEMM M=N(100k) K=768 Ncols=64. 64 rows x 64 cols per block, BK=32, 256 thr, 4x4/thread.
#define BN 64
#define BK 32

__global__ __launch_bounds__(256) void enc_big_kernel(
    const float* __restrict__ des, const float* __restrict__ tweet,
    const float* __restrict__ Wd, const float* __restrict__ bd,
    const float* __restrict__ Wt, const float* __restrict__ bt,
    float* __restrict__ out, int n)
{
    __shared__ float Xd[BN][BK + 4];   // +4 pad: keeps float4 alignment, breaks bank aliasing
    __shared__ float Xt[BN][BK + 4];
    __shared__ float Wl[BK][64];       // cols 0..27 from Wd, 28..63 from Wt
    int n0 = blockIdx.x * BN;
    int cg = threadIdx.x & 15;         // col group: cols cg*4..+3 (0..6 des, 7..15 tweet)
    int rg = threadIdx.x >> 4;         // row group: rows rg*4..+3

    float acc[4][4];
#pragma unroll
    for (int a = 0; a < 4; a++)
#pragma unroll
        for (int b = 0; b < 4; b++) acc[a][b] = 0.f;

    for (int k0 = 0; k0 < 768; k0 += BK) {
        __syncthreads();
        // stage X tiles: 64 rows x 32 k, float4 per thread x2 (rows clamped at tail)
#pragma unroll
        for (int p = 0; p < 2; p++) {
            int idx = threadIdx.x + p * 256;
            int row = idx >> 3, kq = idx & 7;
            int gr = n0 + row; if (gr > n - 1) gr = n - 1;
            float4 vd = *(const float4*)(des   + (size_t)gr * 768 + k0 + kq * 4);
            float4 vt = *(const float4*)(tweet + (size_t)gr * 768 + k0 + kq * 4);
            *(float4*)&Xd[row][kq * 4] = vd;
            *(float4*)&Xt[row][kq * 4] = vt;
        }
        // stage W tile: 32 k x 64 cols (7 des quads + 9 tweet quads per k)
#pragma unroll
        for (int p = 0; p < 2; p++) {
            int idx = threadIdx.x + p * 256;
            int k = idx >> 4, cq = idx & 15;
            float4 w;
            if (cq < 7) w = *(const float4*)(Wd + (size_t)(k0 + k) * 28 + cq * 4);
            else        w = *(const float4*)(Wt + (size_t)(k0 + k) * 36 + (cq - 7) * 4);
            *(float4*)&Wl[k][cq * 4] = w;
        }
        __syncthreads();

        const float* xb = (cg < 7) ? &Xd[0][0] : &Xt[0][0];
#pragma unroll 4
        for (int k = 0; k < BK; k++) {
            float4 w = *(const float4*)&Wl[k][cg * 4];
#pragma unroll
            for (int rr = 0; rr < 4; rr++) {
                float xv = xb[(rg * 4 + rr) * (BK + 4) + k];
                acc[rr][0] += xv * w.x;
                acc[rr][1] += xv * w.y;
                acc[rr][2] += xv * w.z;
                acc[rr][3] += xv * w.w;
            }
        }
    }

    // epilogue: +bias, lrelu, store cols cg*4..+3 of rows n0+rg*4..+3
    float bb[4];
#pragma unroll
    for (int c = 0; c < 4; c++) {
        int j = cg * 4 + c;
        bb[c] = (j < 28) ? bd[j] : bt[j - 28];
    }
#pragma unroll
    for (int rr = 0; rr < 4; rr++) {
        int r = n0 + rg * 4 + rr;
        if (r < n) {
            float4 o;
            o.x = acc[rr][0] + bb[0];
            o.y = acc[rr][1] + bb[1];
            o.z = acc[rr][2] + bb[2];
            o.w = acc[rr][3] + bb[3];
            o.x = o.x > 0.f ? o.x : 0.01f * o.x;
            o.y = o.y > 0.f ? o.y : 0.01f * o.y;
            o.z = o.z > 0.f ? o.z : 0.01f * o.z;
            o.w = o.w > 0.f ? o.w : 0.01f * o.w;
            *(float4*)(out + (size_t)r * 128 + cg * 4) = o;
        }
    }
}

// ================= Encoder small: cols 64..127 (num 12 | cat 40 | new 12) =================
__global__ __launch_bounds__(256) void enc_small_kernel(
    const float* __restrict__ nump, const float* __restrict__ catp,
    const float* __restrict__ nf,
    const float* __restrict__ Wn, const float* __restrict__ bn,
    const float* __restrict__ Wc, const float* __restrict__ bc,
    const float* __restrict__ Ww, const float* __restrict__ bw,
    float* __restrict__ out, int n)
{
    int node = blockIdx.x * 4 + (threadIdx.x >> 6);
    if (node >= n) return;
    int j = threadIdx.x & 63;
    float acc;
    if (j < 12) {
        acc = bn[j];
        for (int k = 0; k < 7; k++) acc += nump[(size_t)node * 7 + k] * Wn[k * 12 + j];
    } else if (j < 52) {
        int c = j - 12;
        acc = bc[c];
        for (int k = 0; k < 11; k++) acc += catp[(size_t)node * 11 + k] * Wc[k * 40 + c];
    } else {
        int c = j - 52;
        acc = bw[c] + nf[node] * Ww[c];
    }
    acc = acc > 0.f ? acc : 0.01f * acc;
    out[(size_t)node * 128 + 64 + j] = acc;
}

// ================= Dense [N,128] @ [128,128] (+bias, +optional lrelu) =================
__global__ __launch_bounds__(256) void dense128_kernel(
    const float* __restrict__ X, const float* __restrict__ W,
    const float* __restrict__ bias, float* __restrict__ Y,
    int nrows, int relu)
{
    __shared__ float Wl[128 * 128];  // 64 KB
    __shared__ float Xl[32 * 128];   // 16 KB
    {
        const float4* W4 = (const float4*)W;
        float4* Wl4 = (float4*)Wl;
        for (int i = threadIdx.x; i < 4096; i += 256) Wl4[i] = W4[i];
    }
    int cg = threadIdx.x & 31;
    int rg = threadIdx.x >> 5;
    int nchunks = (nrows + 31) >> 5;
    for (int chunk = blockIdx.x; chunk < nchunks; chunk += gridDim.x) {
        int base = chunk * 32;
        __syncthreads();
        {
            const float4* X4 = (const float4*)(X + (size_t)base * 128);
            float4* Xl4 = (float4*)Xl;
            for (int i = threadIdx.x; i < 1024; i += 256) Xl4[i] = X4[i];
        }
        __syncthreads();
        float acc[4][4];
#pragma unroll
        for (int a = 0; a < 4; a++)
#pragma unroll
            for (int b = 0; b < 4; b++) acc[a][b] = 0.f;
#pragma unroll 4
        for (int k = 0; k < 128; k++) {
            float4 w = ((const float4*)(Wl + k * 128))[cg];
#pragma unroll
            for (int rr = 0; rr < 4; rr++) {
                float xv = Xl[(rg * 4 + rr) * 128 + k];
                acc[rr][0] += xv * w.x;
                acc[rr][1] += xv * w.y;
                acc[rr][2] += xv * w.z;
                acc[rr][3] += xv * w.w;
            }
        }
        float4 bv;
        if (bias) bv = ((const float4*)bias)[cg];
        else { bv.x = bv.y = bv.z = bv.w = 0.f; }
#pragma unroll
        for (int rr = 0; rr < 4; rr++) {
            float4 o;
            o.x = acc[rr][0] + bv.x;
            o.y = acc[rr][1] + bv.y;
            o.z = acc[rr][2] + bv.z;
            o.w = acc[rr][3] + bv.w;
            if (relu) {
                o.x = o.x > 0.f ? o.x : 0.01f * o.x;
                o.y = o.y > 0.f ? o.y : 0.01f * o.y;
                o.z = o.z > 0.f ? o.z : 0.01f * o.z;
                o.w = o.w > 0.f ? o.w : 0.01f * o.w;
            }
            ((float4*)(Y + (size_t)(base + rg * 4 + rr) * 128))[cg] = o;
        }
    }
}

// ================= CSR build: count -> scan -> fill =================
__global__ void count_kernel(const int* __restrict__ ei, const int* __restrict__ et,
                             int* __restrict__ deg, int E, int N)
{
    int e = blockIdx.x * 256 + threadIdx.x;
    if (e < E) atomicAdd(&deg[(size_t)et[e] * N + ei[E + e]], 1);
}

__global__ void scan1_kernel(const int* __restrict__ deg, int* __restrict__ bsum, int m)
{
    int i = blockIdx.x * 256 + threadIdx.x;
    int v = (i < m) ? deg[i] : 0;
#pragma unroll
    for (int off = 32; off > 0; off >>= 1) v += __shfl_down(v, off);
    __shared__ int ws4[4];
    if ((threadIdx.x & 63) == 0) ws4[threadIdx.x >> 6] = v;
    __syncthreads();
    if (threadIdx.x == 0) bsum[blockIdx.x] = ws4[0] + ws4[1] + ws4[2] + ws4[3];
}

__global__ __launch_bounds__(1024) void scan2_kernel(int* __restrict__ bsum, int nb)
{
    __shared__ int s[1024];
    int t = threadIdx.x;
    int v = (t < nb) ? bsum[t] : 0;
    s[t] = v;
    __syncthreads();
    for (int off = 1; off < 1024; off <<= 1) {
        int u = 0;
        if (t >= off) u = s[t - off];
        __syncthreads();
        s[t] += u;
        __syncthreads();
    }
    if (t < nb) bsum[t] = s[t] - v;  // exclusive block prefix
}

__global__ void scan3_kernel(const int* __restrict__ deg, const int* __restrict__ bsum,
                             int* __restrict__ offs, int m)
{
    __shared__ int s[256];
    int i = blockIdx.x * 256 + threadIdx.x;
    int t = threadIdx.x;
    int v = (i < m) ? deg[i] : 0;
    s[t] = v;
    __syncthreads();
    for (int off = 1; off < 256; off <<= 1) {
        int u = 0;
        if (t >= off) u = s[t - off];
        __syncthreads();
        s[t] += u;
        __syncthreads();
    }
    if (i < m) offs[i] = bsum[blockIdx.x] + s[t] - v;  // global exclusive prefix
}

__global__ void fill_kernel(const int* __restrict__ ei, const int* __restrict__ et,
                            int* __restrict__ offs, int* __restrict__ ord, int E, int N)
{
    int e = blockIdx.x * 256 + threadIdx.x;
    if (e >= E) return;
    int b = et[e] * N + ei[E + e];
    int pos = atomicAdd(&offs[b], 1);   // offs becomes bucket END after this kernel
    ord[pos] = ei[e];                    // src node
}

// ================= Gather: y[d] += mean_{e: dst=d, rel=r} R[src[e]]  (no atomics) =======
// 32 lanes per dst row (float4 each). beg = offs[b-1] (buckets are contiguous), end = offs[b].
__global__ __launch_bounds__(256) void gather_kernel(
    const float* __restrict__ R, const int* __restrict__ offs,
    const int* __restrict__ ord, float* __restrict__ y, int rel, int N)
{
    int d = blockIdx.x * 8 + (threadIdx.x >> 5);
    if (d >= N) return;
    int lane = threadIdx.x & 31;
    int b = rel * N + d;
    int end = offs[b];
    int beg = (b == 0) ? 0 : offs[b - 1];
    float4 acc = {0.f, 0.f, 0.f, 0.f};
    for (int p = beg; p < end; p++) {
        int s = ord[p];
        float4 v = *(const float4*)(R + (size_t)s * 128 + lane * 4);
        acc.x += v.x; acc.y += v.y; acc.z += v.z; acc.w += v.w;
    }
    int dg = end - beg;
    float invd = 1.0f / (float)(dg > 1 ? dg : 1);
    float4* yp = (float4*)(y + (size_t)d * 128) + lane;
    float4 o = *yp;
    o.x += acc.x * invd;
    o.y += acc.y * invd;
    o.z += acc.z * invd;
    o.w += acc.w * invd;
    *yp = o;
}

// ================= Head: out = y @ W_o2 + b_o2 =================
__global__ __launch_bounds__(256) void head_kernel(
    const float* __restrict__ y, const float* __restrict__ W2,
    const float* __restrict__ b2, float* __restrict__ out, int n)
{
    int node = blockIdx.x * 4 + (threadIdx.x >> 6);
    if (node >= n) return;
    int lane = threadIdx.x & 63;
    float x0 = y[(size_t)node * 128 + lane];
    float x1 = y[(size_t)node * 128 + 64 + lane];
    float s0 = x0 * W2[lane * 2]     + x1 * W2[(lane + 64) * 2];
    float s1 = x0 * W2[lane * 2 + 1] + x1 * W2[(lane + 64) * 2 + 1];
#pragma unroll
    for (int off = 32; off > 0; off >>= 1) {
        s0 += __shfl_down(s0, off);
        s1 += __shfl_down(s1, off);
    }
    if (lane == 0) {
        out[(size_t)node * 2]     = s0 + b2[0];
        out[(size_t)node * 2 + 1] = s1 + b2[1];
    }
}

extern "C" void kernel_launch(void* const* d_in, const int* in_sizes, int n_in,
                              void* d_out, int out_size, void* d_ws, size_t ws_size,
                              hipStream_t stream)
{
    const float* des   = (const float*)d_in[0];
    const float* tweet = (const float*)d_in[1];
    const float* nump  = (const float*)d_in[2];
    const float* catp  = (const float*)d_in[3];
    const float* nf    = (const float*)d_in[4];
    const int*   ei    = (const int*)d_in[5];
    const int*   et    = (const int*)d_in[6];
    const float* Wd  = (const float*)d_in[7],  *bd  = (const float*)d_in[8];
    const float* Wt  = (const float*)d_in[9],  *bt  = (const float*)d_in[10];
    const float* Wn  = (const float*)d_in[11], *bn  = (const float*)d_in[12];
    const float* Wc  = (const float*)d_in[13], *bc  = (const float*)d_in[14];
    const float* Ww  = (const float*)d_in[15], *bw  = (const float*)d_in[16];
    const float* Win = (const float*)d_in[17], *bin = (const float*)d_in[18];
    const float* Wroot = (const float*)d_in[19];
    const float* Wrel  = (const float*)d_in[20];
    const float* brg   = (const float*)d_in[21];
    const float* Wo1 = (const float*)d_in[22], *bo1 = (const float*)d_in[23];
    const float* Wo2 = (const float*)d_in[24], *bo2 = (const float*)d_in[25];

    int N = in_sizes[0] / 768;   // 100000
    int E = in_sizes[6];         // 600000

    // ws: P,Q,R [N,128] f32 + CSR aux. Total ~157.6 MB.
    float* P = (float*)d_ws;
    float* Q = P + (size_t)N * 128;
    float* R = Q + (size_t)N * 128;
    int* deg  = (int*)(R + (size_t)N * 128);
    int* offs = deg + (size_t)2 * N;
    int* ord  = offs + (size_t)2 * N;
    int* bsum = ord + (size_t)E;

    int m = 2 * N;                    // buckets
    int nb = (m + 255) / 256;         // 782 <= 1024

    hipMemsetAsync(deg, 0, (size_t)m * sizeof(int), stream);

    // encoder (big GEMM cols 0..63, small features cols 64..127)
    enc_big_kernel<<<(N + BN - 1) / BN, 256, 0, stream>>>(
        des, tweet, Wd, bd, Wt, bt, P, N);
    enc_small_kernel<<<(N + 3) / 4, 256, 0, stream>>>(
        nump, catp, nf, Wn, bn, Wc, bc, Ww, bw, P, N);

    // CSR build (bucket = rel*N + dst)
    count_kernel<<<(E + 255) / 256, 256, 0, stream>>>(ei, et, deg, E, N);
    scan1_kernel<<<nb, 256, 0, stream>>>(deg, bsum, m);
    scan2_kernel<<<1, 1024, 0, stream>>>(bsum, nb);
    scan3_kernel<<<nb, 256, 0, stream>>>(deg, bsum, offs, m);
    fill_kernel<<<(E + 255) / 256, 256, 0, stream>>>(ei, et, offs, ord, E, N);

    int nchunks = (N + 31) / 32;
    // x = lrelu(xcat @ W_in + b_in)
    dense128_kernel<<<nchunks, 256, 0, stream>>>(P, Win, bin, Q, N, 1);

    float* x = Q;
    float* y = P;
    for (int i = 0; i < 4; i++) {
        dense128_kernel<<<nchunks, 256, 0, stream>>>(
            x, Wroot + (size_t)i * 16384, brg + (size_t)i * 128, y, N, 0);
        for (int r = 0; r < 2; r++) {
            dense128_kernel<<<nchunks, 256, 0, stream>>>(
                x, Wrel + (size_t)(i * 2 + r) * 16384, nullptr, R, N, 0);
            gather_kernel<<<(N + 7) / 8, 256, 0, stream>>>(R, offs, ord, y, r, N);
        }
        float* t = x; x = y; y = t;
    }

    dense128_kernel<<<nchunks, 256, 0, stream>>>(x, Wo1, bo1, y, N, 1);
    head_kernel<<<(N + 3) / 4, 256, 0, stream>>>(y, Wo2, bo2, (float*)d_out, N);
}

// Round 3
// 1804.108 us; speedup vs baseline: 2.1711x; 1.2041x over previous
//
#include <hip/hip_runtime.h>

// ================= Encoder big: cols 0..63 = lrelu([des|tweet] @ [Wd|Wt] + b) =================
// 128 rows x 64 cols per block, BK=32, 256 thr, 8x4 per thread (rows interleaved rg + rr*16).
#define EBN 128
#define EBK 32

__global__ __launch_bounds__(256) void enc_big_kernel(
    const float* __restrict__ des, const float* __restrict__ tweet,
    const float* __restrict__ Wd, const float* __restrict__ bd,
    const float* __restrict__ Wt, const float* __restrict__ bt,
    float* __restrict__ out, int n)
{
    __shared__ float Xd[EBN][EBK + 4];   // 18 KB, stride 36 floats (144B, 16B-aligned)
    __shared__ float Xt[EBN][EBK + 4];   // 18 KB
    __shared__ float Wl[EBK][64];        // 8 KB   -> 44 KB total, 3 blocks/CU
    int n0 = blockIdx.x * EBN;
    int cg = threadIdx.x & 15;           // 16 col groups x 4 cols = 64 cols
    int rg = threadIdx.x >> 4;           // 16 row groups; thread rows = rg + rr*16

    float acc[8][4];
#pragma unroll
    for (int a = 0; a < 8; a++)
#pragma unroll
        for (int b = 0; b < 4; b++) acc[a][b] = 0.f;

    for (int k0 = 0; k0 < 768; k0 += EBK) {
        __syncthreads();
        // stage X tiles: 128 rows x 32 k each; 4 float4 per thread per matrix
#pragma unroll
        for (int pass = 0; pass < 4; pass++) {
            int idx = threadIdx.x + pass * 256;     // 0..1023
            int row = idx >> 3, kq = idx & 7;
            int gr = n0 + row; if (gr >= n) gr = n - 1;
            *(float4*)&Xd[row][kq * 4] = *(const float4*)(des   + (size_t)gr * 768 + k0 + kq * 4);
            *(float4*)&Xt[row][kq * 4] = *(const float4*)(tweet + (size_t)gr * 768 + k0 + kq * 4);
        }
        // stage W tile: 32 k x 64 cols
#pragma unroll
        for (int pass = 0; pass < 2; pass++) {
            int idx = threadIdx.x + pass * 256;     // 0..511
            int k = idx >> 4, cq = idx & 15;
            float4 w;
            if (cq < 7) w = *(const float4*)(Wd + (size_t)(k0 + k) * 28 + cq * 4);
            else        w = *(const float4*)(Wt + (size_t)(k0 + k) * 36 + (cq - 7) * 4);
            *(float4*)&Wl[k][cq * 4] = w;
        }
        __syncthreads();

        const float* xb = (cg < 7) ? &Xd[0][0] : &Xt[0][0];
#pragma unroll
        for (int kq = 0; kq < 8; kq++) {
            float4 xv[8];
#pragma unroll
            for (int rr = 0; rr < 8; rr++)
                xv[rr] = *(const float4*)&xb[(rg + rr * 16) * (EBK + 4) + kq * 4];
#pragma unroll
            for (int kk = 0; kk < 4; kk++) {
                float4 w = *(const float4*)&Wl[kq * 4 + kk][cg * 4];
#pragma unroll
                for (int rr = 0; rr < 8; rr++) {
                    float xs = (kk == 0) ? xv[rr].x : (kk == 1) ? xv[rr].y : (kk == 2) ? xv[rr].z : xv[rr].w;
                    acc[rr][0] += xs * w.x;
                    acc[rr][1] += xs * w.y;
                    acc[rr][2] += xs * w.z;
                    acc[rr][3] += xs * w.w;
                }
            }
        }
    }

    float bb[4];
#pragma unroll
    for (int c = 0; c < 4; c++) {
        int j = cg * 4 + c;
        bb[c] = (j < 28) ? bd[j] : bt[j - 28];
    }
#pragma unroll
    for (int rr = 0; rr < 8; rr++) {
        int r = n0 + rg + rr * 16;
        if (r < n) {
            float4 o;
            o.x = acc[rr][0] + bb[0];
            o.y = acc[rr][1] + bb[1];
            o.z = acc[rr][2] + bb[2];
            o.w = acc[rr][3] + bb[3];
            o.x = o.x > 0.f ? o.x : 0.01f * o.x;
            o.y = o.y > 0.f ? o.y : 0.01f * o.y;
            o.z = o.z > 0.f ? o.z : 0.01f * o.z;
            o.w = o.w > 0.f ? o.w : 0.01f * o.w;
            *(float4*)(out + (size_t)r * 128 + cg * 4) = o;
        }
    }
}

// ================= Encoder small: cols 64..127 (num 12 | cat 40 | new 12) =================
__global__ __launch_bounds__(256) void enc_small_kernel(
    const float* __restrict__ nump, const float* __restrict__ catp,
    const float* __restrict__ nf,
    const float* __restrict__ Wn, const float* __restrict__ bn,
    const float* __restrict__ Wc, const float* __restrict__ bc,
    const float* __restrict__ Ww, const float* __restrict__ bw,
    float* __restrict__ out, int n)
{
    int node = blockIdx.x * 4 + (threadIdx.x >> 6);
    if (node >= n) return;
    int j = threadIdx.x & 63;
    float acc;
    if (j < 12) {
        acc = bn[j];
        for (int k = 0; k < 7; k++) acc += nump[(size_t)node * 7 + k] * Wn[k * 12 + j];
    } else if (j < 52) {
        int c = j - 12;
        acc = bc[c];
        for (int k = 0; k < 11; k++) acc += catp[(size_t)node * 11 + k] * Wc[k * 40 + c];
    } else {
        int c = j - 52;
        acc = bw[c] + nf[node] * Ww[c];
    }
    acc = acc > 0.f ? acc : 0.01f * acc;
    out[(size_t)node * 128 + 64 + j] = acc;
}

// ================= Fused multi-phase dense: out = sum_p in_p @ W_p + b  (in-place safe) ======
// 32-row chunks, 256 thr, 4x4/thread. W staged per phase in 64-k halves (32 KB).
__global__ __launch_bounds__(256) void dense_multi_kernel(
    const float* __restrict__ in0, const float* __restrict__ in1, const float* __restrict__ in2,
    int s0, int o0, int s1, int o1, int s2, int o2,
    const float* __restrict__ W0, const float* __restrict__ W1, const float* __restrict__ W2,
    const float* __restrict__ bias, float* __restrict__ out,
    int nphases, int relu)
{
    __shared__ float Wl[64][128];        // 32 KB
    __shared__ float Xl[32][132];        // 16.5 KB  (stride 132: 528B, 16B-aligned; rg-span 528%128B=16 banks -> conflict-free)
    int base = blockIdx.x * 32;
    int cg = threadIdx.x & 31;           // 32 col groups x 4 = 128 cols
    int rg = threadIdx.x >> 5;           // 8 row groups x 4 = 32 rows

    float acc[4][4];
#pragma unroll
    for (int a = 0; a < 4; a++)
#pragma unroll
        for (int b = 0; b < 4; b++) acc[a][b] = 0.f;

    for (int p = 0; p < nphases; p++) {
        const float* inp = (p == 0) ? in0 : (p == 1) ? in1 : in2;
        const float* Wp  = (p == 0) ? W0  : (p == 1) ? W1  : W2;
        int st  = (p == 0) ? s0 : (p == 1) ? s1 : s2;
        int off = (p == 0) ? o0 : (p == 1) ? o1 : o2;
        for (int half = 0; half < 2; half++) {
            __syncthreads();  // previous compute (or previous chunk state) done
            if (half == 0) {
                // stage X tile: 32 rows x 128 k
#pragma unroll
                for (int pass = 0; pass < 4; pass++) {
                    int idx = threadIdx.x + pass * 256;     // 0..1023
                    int row = idx >> 5, kq = idx & 31;
                    *(float4*)&Xl[row][kq * 4] =
                        *(const float4*)(inp + (size_t)(base + row) * st + off + kq * 4);
                }
            }
            // stage W half: 64 k x 128 cols
#pragma unroll
            for (int pass = 0; pass < 8; pass++) {
                int idx = threadIdx.x + pass * 256;          // 0..2047
                int row = idx >> 5, cq = idx & 31;
                *(float4*)&Wl[row][cq * 4] =
                    *(const float4*)(Wp + (size_t)(half * 64 + row) * 128 + cq * 4);
            }
            __syncthreads();
#pragma unroll 2
            for (int kq = 0; kq < 16; kq++) {
                float4 xv[4];
#pragma unroll
                for (int rr = 0; rr < 4; rr++)
                    xv[rr] = *(const float4*)&Xl[rg * 4 + rr][(half * 16 + kq) * 4];
#pragma unroll
                for (int kk = 0; kk < 4; kk++) {
                    float4 w = *(const float4*)&Wl[kq * 4 + kk][cg * 4];
#pragma unroll
                    for (int rr = 0; rr < 4; rr++) {
                        float xs = (kk == 0) ? xv[rr].x : (kk == 1) ? xv[rr].y : (kk == 2) ? xv[rr].z : xv[rr].w;
                        acc[rr][0] += xs * w.x;
                        acc[rr][1] += xs * w.y;
                        acc[rr][2] += xs * w.z;
                        acc[rr][3] += xs * w.w;
                    }
                }
            }
        }
    }

    float4 bv = ((const float4*)bias)[cg];
#pragma unroll
    for (int rr = 0; rr < 4; rr++) {
        float4 o;
        o.x = acc[rr][0] + bv.x;
        o.y = acc[rr][1] + bv.y;
        o.z = acc[rr][2] + bv.z;
        o.w = acc[rr][3] + bv.w;
        if (relu) {
            o.x = o.x > 0.f ? o.x : 0.01f * o.x;
            o.y = o.y > 0.f ? o.y : 0.01f * o.y;
            o.z = o.z > 0.f ? o.z : 0.01f * o.z;
            o.w = o.w > 0.f ? o.w : 0.01f * o.w;
        }
        *(float4*)(out + (size_t)(base + rg * 4 + rr) * 128 + cg * 4) = o;
    }
}

// ================= CSR build: count -> scan -> fill =================
__global__ void count_kernel(const int* __restrict__ ei, const int* __restrict__ et,
                             int* __restrict__ deg, int E, int N)
{
    int e = blockIdx.x * 256 + threadIdx.x;
    if (e < E) atomicAdd(&deg[(size_t)et[e] * N + ei[E + e]], 1);
}

__global__ void scan1_kernel(const int* __restrict__ deg, int* __restrict__ bsum, int m)
{
    int i = blockIdx.x * 256 + threadIdx.x;
    int v = (i < m) ? deg[i] : 0;
#pragma unroll
    for (int off = 32; off > 0; off >>= 1) v += __shfl_down(v, off);
    __shared__ int ws4[4];
    if ((threadIdx.x & 63) == 0) ws4[threadIdx.x >> 6] = v;
    __syncthreads();
    if (threadIdx.x == 0) bsum[blockIdx.x] = ws4[0] + ws4[1] + ws4[2] + ws4[3];
}

__global__ __launch_bounds__(1024) void scan2_kernel(int* __restrict__ bsum, int nb)
{
    __shared__ int s[1024];
    int t = threadIdx.x;
    int v = (t < nb) ? bsum[t] : 0;
    s[t] = v;
    __syncthreads();
    for (int off = 1; off < 1024; off <<= 1) {
        int u = 0;
        if (t >= off) u = s[t - off];
        __syncthreads();
        s[t] += u;
        __syncthreads();
    }
    if (t < nb) bsum[t] = s[t] - v;  // exclusive block prefix
}

__global__ void scan3_kernel(const int* __restrict__ deg, const int* __restrict__ bsum,
                             int* __restrict__ offs, int m)
{
    __shared__ int s[256];
    int i = blockIdx.x * 256 + threadIdx.x;
    int t = threadIdx.x;
    int v = (i < m) ? deg[i] : 0;
    s[t] = v;
    __syncthreads();
    for (int off = 1; off < 256; off <<= 1) {
        int u = 0;
        if (t >= off) u = s[t - off];
        __syncthreads();
        s[t] += u;
        __syncthreads();
    }
    if (i < m) offs[i] = bsum[blockIdx.x] + s[t] - v;  // global exclusive prefix
}

__global__ void fill_kernel(const int* __restrict__ ei, const int* __restrict__ et,
                            int* __restrict__ offs, int* __restrict__ ord, int E, int N)
{
    int e = blockIdx.x * 256 + threadIdx.x;
    if (e >= E) return;
    int b = et[e] * N + ei[E + e];
    int pos = atomicAdd(&offs[b], 1);   // offs becomes bucket END after this kernel
    ord[pos] = ei[e];                    // src node
}

// ============ Combined 2-relation mean-gather: G[d] = [mean_r0(x[src]) | mean_r1(x[src])] ====
__global__ __launch_bounds__(256) void gather2_kernel(
    const float* __restrict__ x, const int* __restrict__ offs,
    const int* __restrict__ ord, float* __restrict__ G, int N)
{
    int d = blockIdx.x * 8 + (threadIdx.x >> 5);
    if (d >= N) return;
    int lane = threadIdx.x & 31;
#pragma unroll
    for (int r = 0; r < 2; r++) {
        int b = r * N + d;
        int end = offs[b];
        int beg = (b == 0) ? 0 : offs[b - 1];
        float4 acc = {0.f, 0.f, 0.f, 0.f};
        for (int p = beg; p < end; p++) {
            int s = ord[p];
            float4 v = *(const float4*)(x + (size_t)s * 128 + lane * 4);
            acc.x += v.x; acc.y += v.y; acc.z += v.z; acc.w += v.w;
        }
        int dg = end - beg;
        float invd = 1.0f / (float)(dg > 1 ? dg : 1);
        float4 o;
        o.x = acc.x * invd; o.y = acc.y * invd; o.z = acc.z * invd; o.w = acc.w * invd;
        *(float4*)(G + (size_t)d * 256 + r * 128 + lane * 4) = o;
    }
}

// ================= Head: out = y @ W_o2 + b_o2 =================
__global__ __launch_bounds__(256) void head_kernel(
    const float* __restrict__ y, const float* __restrict__ W2,
    const float* __restrict__ b2, float* __restrict__ out, int n)
{
    int node = blockIdx.x * 4 + (threadIdx.x >> 6);
    if (node >= n) return;
    int lane = threadIdx.x & 63;
    float x0 = y[(size_t)node * 128 + lane];
    float x1 = y[(size_t)node * 128 + 64 + lane];
    float s0 = x0 * W2[lane * 2]     + x1 * W2[(lane + 64) * 2];
    float s1 = x0 * W2[lane * 2 + 1] + x1 * W2[(lane + 64) * 2 + 1];
#pragma unroll
    for (int off = 32; off > 0; off >>= 1) {
        s0 += __shfl_down(s0, off);
        s1 += __shfl_down(s1, off);
    }
    if (lane == 0) {
        out[(size_t)node * 2]     = s0 + b2[0];
        out[(size_t)node * 2 + 1] = s1 + b2[1];
    }
}

extern "C" void kernel_launch(void* const* d_in, const int* in_sizes, int n_in,
                              void* d_out, int out_size, void* d_ws, size_t ws_size,
                              hipStream_t stream)
{
    const float* des   = (const float*)d_in[0];
    const float* tweet = (const float*)d_in[1];
    const float* nump  = (const float*)d_in[2];
    const float* catp  = (const float*)d_in[3];
    const float* nf    = (const float*)d_in[4];
    const int*   ei    = (const int*)d_in[5];
    const int*   et    = (const int*)d_in[6];
    const float* Wd  = (const float*)d_in[7],  *bd  = (const float*)d_in[8];
    const float* Wt  = (const float*)d_in[9],  *bt  = (const float*)d_in[10];
    const float* Wn  = (const float*)d_in[11], *bn  = (const float*)d_in[12];
    const float* Wc  = (const float*)d_in[13], *bc  = (const float*)d_in[14];
    const float* Ww  = (const float*)d_in[15], *bw  = (const float*)d_in[16];
    const float* Win = (const float*)d_in[17], *bin = (const float*)d_in[18];
    const float* Wroot = (const float*)d_in[19];
    const float* Wrel  = (const float*)d_in[20];
    const float* brg   = (const float*)d_in[21];
    const float* Wo1 = (const float*)d_in[22], *bo1 = (const float*)d_in[23];
    const float* Wo2 = (const float*)d_in[24], *bo2 = (const float*)d_in[25];

    int N = in_sizes[0] / 768;   // 100000
    int E = in_sizes[6];         // 600000

    // ws: x [N,128] f32 | G [N,256] f32 | CSR ints. Total 157.7 MB (same as R2's 157.6).
    float* x = (float*)d_ws;
    float* G = x + (size_t)N * 128;
    int* deg  = (int*)(G + (size_t)N * 256);
    int* offs = deg + (size_t)2 * N;
    int* ord  = offs + (size_t)2 * N;
    int* bsum = ord + (size_t)E;

    int m = 2 * N;
    int nb = (m + 255) / 256;         // 782 <= 1024

    hipMemsetAsync(deg, 0, (size_t)m * sizeof(int), stream);

    // encoder -> x (cols 0..63 big, 64..127 small)
    enc_big_kernel<<<(N + EBN - 1) / EBN, 256, 0, stream>>>(
        des, tweet, Wd, bd, Wt, bt, x, N);
    enc_small_kernel<<<(N + 3) / 4, 256, 0, stream>>>(
        nump, catp, nf, Wn, bn, Wc, bc, Ww, bw, x, N);

    // CSR build (bucket = rel*N + dst)
    count_kernel<<<(E + 255) / 256, 256, 0, stream>>>(ei, et, deg, E, N);
    scan1_kernel<<<nb, 256, 0, stream>>>(deg, bsum, m);
    scan2_kernel<<<1, 1024, 0, stream>>>(bsum, nb);
    scan3_kernel<<<nb, 256, 0, stream>>>(deg, bsum, offs, m);
    fill_kernel<<<(E + 255) / 256, 256, 0, stream>>>(ei, et, offs, ord, E, N);

    int nchunks = N / 32;  // 3125 exact
    // x = lrelu(x @ W_in + b_in)   (in-place, 1 phase)
    dense_multi_kernel<<<nchunks, 256, 0, stream>>>(
        x, x, x, 128, 0, 128, 0, 128, 0, Win, Win, Win, bin, x, 1, 1);

    for (int i = 0; i < 4; i++) {
        // G = [mean_r0(x[src]) | mean_r1(x[src])]
        gather2_kernel<<<(N + 7) / 8, 256, 0, stream>>>(x, offs, ord, G, N);
        // x = x @ W_root[i] + G0 @ W_rel[i][0] + G1 @ W_rel[i][1] + b   (in-place, 3 phases)
        dense_multi_kernel<<<nchunks, 256, 0, stream>>>(
            x, G, G, 128, 0, 256, 0, 256, 128,
            Wroot + (size_t)i * 16384,
            Wrel + (size_t)(i * 2 + 0) * 16384,
            Wrel + (size_t)(i * 2 + 1) * 16384,
            brg + (size_t)i * 128, x, 3, 0);
    }

    // x = lrelu(x @ W_o1 + b_o1)   (in-place)
    dense_multi_kernel<<<nchunks, 256, 0, stream>>>(
        x, x, x, 128, 0, 128, 0, 128, 0, Wo1, Wo1, Wo1, bo1, x, 1, 1);
    // out = x @ W_o2 + b_o2
    head_kernel<<<(N + 3) / 4, 256, 0, stream>>>(x, Wo2, bo2, (float*)d_out, N);
}

// Round 4
// 1478.583 us; speedup vs baseline: 2.6491x; 1.2202x over previous
//
#include <hip/hip_runtime.h>

typedef __attribute__((ext_vector_type(8))) short short8;   // 8 bf16 = 4 VGPRs (MFMA A/B frag)
typedef __attribute__((ext_vector_type(4))) float floatx4;  // MFMA C/D frag

// split fp32 v ~= hi + lo (both bf16). hi = RN(v), lo = trunc(v - hi). rel err ~2^-17.
__device__ inline void split_bf16(float v, unsigned short &h, unsigned short &l) {
    unsigned u = __float_as_uint(v);
    unsigned hu = (u + 0x8000u) & 0xFFFF0000u;
    h = (unsigned short)(hu >> 16);
    float lf = v - __uint_as_float(hu);
    l = (unsigned short)(__float_as_uint(lf) >> 16);
}

// ================= Encoder big (R2 verbatim: 64 rows, 4x4/thread, 40 VGPR, occ 51%) ========
#define BN 64
#define BK 32

__global__ __launch_bounds__(256) void enc_big_kernel(
    const float* __restrict__ des, const float* __restrict__ tweet,
    const float* __restrict__ Wd, const float* __restrict__ bd,
    const float* __restrict__ Wt, const float* __restrict__ bt,
    float* __restrict__ out, int n)
{
    __shared__ float Xd[BN][BK + 4];
    __shared__ float Xt[BN][BK + 4];
    __shared__ float Wl[BK][64];
    int n0 = blockIdx.x * BN;
    int cg = threadIdx.x & 15;
    int rg = threadIdx.x >> 4;

    float acc[4][4];
#pragma unroll
    for (int a = 0; a < 4; a++)
#pragma unroll
        for (int b = 0; b < 4; b++) acc[a][b] = 0.f;

    for (int k0 = 0; k0 < 768; k0 += BK) {
        __syncthreads();
#pragma unroll
        for (int p = 0; p < 2; p++) {
            int idx = threadIdx.x + p * 256;
            int row = idx >> 3, kq = idx & 7;
            int gr = n0 + row; if (gr > n - 1) gr = n - 1;
            float4 vd = *(const float4*)(des   + (size_t)gr * 768 + k0 + kq * 4);
            float4 vt = *(const float4*)(tweet + (size_t)gr * 768 + k0 + kq * 4);
            *(float4*)&Xd[row][kq * 4] = vd;
            *(float4*)&Xt[row][kq * 4] = vt;
        }
#pragma unroll
        for (int p = 0; p < 2; p++) {
            int idx = threadIdx.x + p * 256;
            int k = idx >> 4, cq = idx & 15;
            float4 w;
            if (cq < 7) w = *(const float4*)(Wd + (size_t)(k0 + k) * 28 + cq * 4);
            else        w = *(const float4*)(Wt + (size_t)(k0 + k) * 36 + (cq - 7) * 4);
            *(float4*)&Wl[k][cq * 4] = w;
        }
        __syncthreads();

        const float* xb = (cg < 7) ? &Xd[0][0] : &Xt[0][0];
#pragma unroll 4
        for (int k = 0; k < BK; k++) {
            float4 w = *(const float4*)&Wl[k][cg * 4];
#pragma unroll
            for (int rr = 0; rr < 4; rr++) {
                float xv = xb[(rg * 4 + rr) * (BK + 4) + k];
                acc[rr][0] += xv * w.x;
                acc[rr][1] += xv * w.y;
                acc[rr][2] += xv * w.z;
                acc[rr][3] += xv * w.w;
            }
        }
    }

    float bb[4];
#pragma unroll
    for (int c = 0; c < 4; c++) {
        int j = cg * 4 + c;
        bb[c] = (j < 28) ? bd[j] : bt[j - 28];
    }
#pragma unroll
    for (int rr = 0; rr < 4; rr++) {
        int r = n0 + rg * 4 + rr;
        if (r < n) {
            float4 o;
            o.x = acc[rr][0] + bb[0];
            o.y = acc[rr][1] + bb[1];
            o.z = acc[rr][2] + bb[2];
            o.w = acc[rr][3] + bb[3];
            o.x = o.x > 0.f ? o.x : 0.01f * o.x;
            o.y = o.y > 0.f ? o.y : 0.01f * o.y;
            o.z = o.z > 0.f ? o.z : 0.01f * o.z;
            o.w = o.w > 0.f ? o.w : 0.01f * o.w;
            *(float4*)(out + (size_t)r * 128 + cg * 4) = o;
        }
    }
}

// ================= Encoder small: cols 64..127 =================
__global__ __launch_bounds__(256) void enc_small_kernel(
    const float* __restrict__ nump, const float* __restrict__ catp,
    const float* __restrict__ nf,
    const float* __restrict__ Wn, const float* __restrict__ bn,
    const float* __restrict__ Wc, const float* __restrict__ bc,
    const float* __restrict__ Ww, const float* __restrict__ bw,
    float* __restrict__ out, int n)
{
    int node = blockIdx.x * 4 + (threadIdx.x >> 6);
    if (node >= n) return;
    int j = threadIdx.x & 63;
    float acc;
    if (j < 12) {
        acc = bn[j];
        for (int k = 0; k < 7; k++) acc += nump[(size_t)node * 7 + k] * Wn[k * 12 + j];
    } else if (j < 52) {
        int c = j - 12;
        acc = bc[c];
        for (int k = 0; k < 11; k++) acc += catp[(size_t)node * 11 + k] * Wc[k * 40 + c];
    } else {
        int c = j - 52;
        acc = bw[c] + nf[node] * Ww[c];
    }
    acc = acc > 0.f ? acc : 0.01f * acc;
    out[(size_t)node * 128 + 64 + j] = acc;
}

// ===== Weight prep: transpose + bf16-split. dst[m][col][k] = split(src[m][k][col]) =====
__global__ void prep_w_kernel(const float* __restrict__ src,
                              unsigned short* __restrict__ dh,
                              unsigned short* __restrict__ dl, int total)
{
    int idx = blockIdx.x * 256 + threadIdx.x;
    if (idx >= total) return;
    int m = idx >> 14, r = idx & 16383;
    int k = r >> 7, col = r & 127;
    unsigned short h, l;
    split_bf16(src[idx], h, l);
    int didx = (m << 14) | (col << 7) | k;
    dh[didx] = h; dl[didx] = l;
}

// ===== MFMA multi-phase dense: out = sum_p in_p @ W_p + b (fp32 via bf16 hi/lo 3-mult) =====
// 64 rows x 128 cols/block, 4 waves: wave w = rows 0..63 (4 tiles) x cols w*32..+31 (2 tiles).
// W pre-transposed [col][k] (B-frag order) read from global (L2). X staged fp32->split in LDS.
__global__ __launch_bounds__(256) void dense_mfma_kernel(
    const float* __restrict__ in0, const float* __restrict__ in1, const float* __restrict__ in2,
    int s0, int o0, int s1, int o1, int s2, int o2,
    const unsigned short* __restrict__ Wh, const unsigned short* __restrict__ Wl,
    int slot0, int slot1, int slot2,
    const float* __restrict__ bias, float* __restrict__ out,
    int nphases, int relu, int N)
{
    __shared__ unsigned short Xh[64][136];   // 17 KB (row stride 272B: 16B-aligned frags)
    __shared__ unsigned short Xl[64][136];   // 17 KB
    int base = blockIdx.x * 64;
    int lane = threadIdx.x & 63;
    int wv   = threadIdx.x >> 6;
    int srow = threadIdx.x >> 2;      // staging: row 0..63
    int sseg = threadIdx.x & 3;       // staging: 32-col segment
    int mrow = lane & 15;             // A row / B col / D col within tile
    int quad = lane >> 4;

    floatx4 acc[4][2];
#pragma unroll
    for (int t = 0; t < 4; t++)
#pragma unroll
        for (int ct = 0; ct < 2; ct++) acc[t][ct] = (floatx4){0.f, 0.f, 0.f, 0.f};

    for (int p = 0; p < nphases; p++) {
        const float* inp = (p == 0) ? in0 : (p == 1) ? in1 : in2;
        int st   = (p == 0) ? s0 : (p == 1) ? s1 : s2;
        int off  = (p == 0) ? o0 : (p == 1) ? o1 : o2;
        int slot = (p == 0) ? slot0 : (p == 1) ? slot1 : slot2;

        __syncthreads();   // prior phase's frag reads done before restaging
        {
            int gr = base + srow; if (gr >= N) gr = N - 1;
            const float* src = inp + (size_t)gr * st + off + sseg * 32;
            unsigned short th[32], tl[32];
#pragma unroll
            for (int q = 0; q < 8; q++) {
                float4 v = *(const float4*)(src + q * 4);
                split_bf16(v.x, th[q * 4 + 0], tl[q * 4 + 0]);
                split_bf16(v.y, th[q * 4 + 1], tl[q * 4 + 1]);
                split_bf16(v.z, th[q * 4 + 2], tl[q * 4 + 2]);
                split_bf16(v.w, th[q * 4 + 3], tl[q * 4 + 3]);
            }
#pragma unroll
            for (int q = 0; q < 4; q++) {
                *(short8*)&Xh[srow][sseg * 32 + q * 8] = *(short8*)&th[q * 8];
                *(short8*)&Xl[srow][sseg * 32 + q * 8] = *(short8*)&tl[q * 8];
            }
        }
        __syncthreads();

        const unsigned short* wh = Wh + (size_t)slot * 16384;
        const unsigned short* wl = Wl + (size_t)slot * 16384;
#pragma unroll
        for (int ks = 0; ks < 4; ks++) {
            int kk = ks * 32 + quad * 8;
            short8 ah[4], al[4];
#pragma unroll
            for (int t = 0; t < 4; t++) {
                ah[t] = *(const short8*)&Xh[t * 16 + mrow][kk];
                al[t] = *(const short8*)&Xl[t * 16 + mrow][kk];
            }
#pragma unroll
            for (int ct = 0; ct < 2; ct++) {
                int col = wv * 32 + ct * 16 + mrow;
                short8 bh = *(const short8*)(wh + col * 128 + kk);
                short8 bl = *(const short8*)(wl + col * 128 + kk);
#pragma unroll
                for (int t = 0; t < 4; t++) {
                    acc[t][ct] = __builtin_amdgcn_mfma_f32_16x16x32_bf16(ah[t], bh, acc[t][ct], 0, 0, 0);
                    acc[t][ct] = __builtin_amdgcn_mfma_f32_16x16x32_bf16(ah[t], bl, acc[t][ct], 0, 0, 0);
                    acc[t][ct] = __builtin_amdgcn_mfma_f32_16x16x32_bf16(al[t], bh, acc[t][ct], 0, 0, 0);
                }
            }
        }
    }

    // epilogue: D layout col=lane&15, row=quad*4+reg
#pragma unroll
    for (int ct = 0; ct < 2; ct++) {
        int col = wv * 32 + ct * 16 + mrow;
        float bv = bias[col];
#pragma unroll
        for (int t = 0; t < 4; t++) {
#pragma unroll
            for (int rg = 0; rg < 4; rg++) {
                int r = base + t * 16 + quad * 4 + rg;
                if (r < N) {
                    float v = acc[t][ct][rg] + bv;
                    if (relu) v = v > 0.f ? v : 0.01f * v;
                    out[(size_t)r * 128 + col] = v;
                }
            }
        }
    }
}

// ================= CSR build: count -> scan -> fill =================
__global__ void count_kernel(const int* __restrict__ ei, const int* __restrict__ et,
                             int* __restrict__ deg, int E, int N)
{
    int e = blockIdx.x * 256 + threadIdx.x;
    if (e < E) atomicAdd(&deg[(size_t)et[e] * N + ei[E + e]], 1);
}

__global__ void scan1_kernel(const int* __restrict__ deg, int* __restrict__ bsum, int m)
{
    int i = blockIdx.x * 256 + threadIdx.x;
    int v = (i < m) ? deg[i] : 0;
#pragma unroll
    for (int off = 32; off > 0; off >>= 1) v += __shfl_down(v, off);
    __shared__ int ws4[4];
    if ((threadIdx.x & 63) == 0) ws4[threadIdx.x >> 6] = v;
    __syncthreads();
    if (threadIdx.x == 0) bsum[blockIdx.x] = ws4[0] + ws4[1] + ws4[2] + ws4[3];
}

__global__ __launch_bounds__(1024) void scan2_kernel(int* __restrict__ bsum, int nb)
{
    __shared__ int s[1024];
    int t = threadIdx.x;
    int v = (t < nb) ? bsum[t] : 0;
    s[t] = v;
    __syncthreads();
    for (int off = 1; off < 1024; off <<= 1) {
        int u = 0;
        if (t >= off) u = s[t - off];
        __syncthreads();
        s[t] += u;
        __syncthreads();
    }
    if (t < nb) bsum[t] = s[t] - v;
}

__global__ void scan3_kernel(const int* __restrict__ deg, const int* __restrict__ bsum,
                             int* __restrict__ offs, int m)
{
    __shared__ int s[256];
    int i = blockIdx.x * 256 + threadIdx.x;
    int t = threadIdx.x;
    int v = (i < m) ? deg[i] : 0;
    s[t] = v;
    __syncthreads();
    for (int off = 1; off < 256; off <<= 1) {
        int u = 0;
        if (t >= off) u = s[t - off];
        __syncthreads();
        s[t] += u;
        __syncthreads();
    }
    if (i < m) offs[i] = bsum[blockIdx.x] + s[t] - v;
}

__global__ void fill_kernel(const int* __restrict__ ei, const int* __restrict__ et,
                            int* __restrict__ offs, int* __restrict__ ord, int E, int N)
{
    int e = blockIdx.x * 256 + threadIdx.x;
    if (e >= E) return;
    int b = et[e] * N + ei[E + e];
    int pos = atomicAdd(&offs[b], 1);
    ord[pos] = ei[e];
}

// ============ Combined 2-relation mean-gather ============
__global__ __launch_bounds__(256) void gather2_kernel(
    const float* __restrict__ x, const int* __restrict__ offs,
    const int* __restrict__ ord, float* __restrict__ G, int N)
{
    int d = blockIdx.x * 8 + (threadIdx.x >> 5);
    if (d >= N) return;
    int lane = threadIdx.x & 31;
#pragma unroll
    for (int r = 0; r < 2; r++) {
        int b = r * N + d;
        int end = offs[b];
        int beg = (b == 0) ? 0 : offs[b - 1];
        float4 acc = {0.f, 0.f, 0.f, 0.f};
        for (int p = beg; p < end; p++) {
            int s = ord[p];
            float4 v = *(const float4*)(x + (size_t)s * 128 + lane * 4);
            acc.x += v.x; acc.y += v.y; acc.z += v.z; acc.w += v.w;
        }
        int dg = end - beg;
        float invd = 1.0f / (float)(dg > 1 ? dg : 1);
        float4 o;
        o.x = acc.x * invd; o.y = acc.y * invd; o.z = acc.z * invd; o.w = acc.w * invd;
        *(float4*)(G + (size_t)d * 256 + r * 128 + lane * 4) = o;
    }
}

// ================= Head =================
__global__ __launch_bounds__(256) void head_kernel(
    const float* __restrict__ y, const float* __restrict__ W2,
    const float* __restrict__ b2, float* __restrict__ out, int n)
{
    int node = blockIdx.x * 4 + (threadIdx.x >> 6);
    if (node >= n) return;
    int lane = threadIdx.x & 63;
    float x0 = y[(size_t)node * 128 + lane];
    float x1 = y[(size_t)node * 128 + 64 + lane];
    float s0 = x0 * W2[lane * 2]     + x1 * W2[(lane + 64) * 2];
    float s1 = x0 * W2[lane * 2 + 1] + x1 * W2[(lane + 64) * 2 + 1];
#pragma unroll
    for (int off = 32; off > 0; off >>= 1) {
        s0 += __shfl_down(s0, off);
        s1 += __shfl_down(s1, off);
    }
    if (lane == 0) {
        out[(size_t)node * 2]     = s0 + b2[0];
        out[(size_t)node * 2 + 1] = s1 + b2[1];
    }
}

extern "C" void kernel_launch(void* const* d_in, const int* in_sizes, int n_in,
                              void* d_out, int out_size, void* d_ws, size_t ws_size,
                              hipStream_t stream)
{
    const float* des   = (const float*)d_in[0];
    const float* tweet = (const float*)d_in[1];
    const float* nump  = (const float*)d_in[2];
    const float* catp  = (const float*)d_in[3];
    const float* nf    = (const float*)d_in[4];
    const int*   ei    = (const int*)d_in[5];
    const int*   et    = (const int*)d_in[6];
    const float* Wd  = (const float*)d_in[7],  *bd  = (const float*)d_in[8];
    const float* Wt  = (const float*)d_in[9],  *bt  = (const float*)d_in[10];
    const float* Wn  = (const float*)d_in[11], *bn  = (const float*)d_in[12];
    const float* Wc  = (const float*)d_in[13], *bc  = (const float*)d_in[14];
    const float* Ww  = (const float*)d_in[15], *bw  = (const float*)d_in[16];
    const float* Win = (const float*)d_in[17], *bin = (const float*)d_in[18];
    const float* Wroot = (const float*)d_in[19];
    const float* Wrel  = (const float*)d_in[20];
    const float* brg   = (const float*)d_in[21];
    const float* Wo1 = (const float*)d_in[22], *bo1 = (const float*)d_in[23];
    const float* Wo2 = (const float*)d_in[24], *bo2 = (const float*)d_in[25];

    int N = in_sizes[0] / 768;   // 100000
    int E = in_sizes[6];         // 600000

    // ws: x[N*128] f32 | G[N*256] f32 | Wth/Wtl 14*16384 u16 | CSR ints. ~158.5 MB.
    float* x = (float*)d_ws;
    float* G = x + (size_t)N * 128;
    unsigned short* Wth = (unsigned short*)(G + (size_t)N * 256);
    unsigned short* Wtl = Wth + (size_t)14 * 16384;
    int* deg  = (int*)(Wtl + (size_t)14 * 16384);
    int* offs = deg + (size_t)2 * N;
    int* ord  = offs + (size_t)2 * N;
    int* bsum = ord + (size_t)E;

    int m = 2 * N;
    int nb = (m + 255) / 256;         // 782 <= 1024

    hipMemsetAsync(deg, 0, (size_t)m * sizeof(int), stream);

    // weight prep: slots [0]=Win [1..4]=Wroot [5..12]=Wrel [13]=Wo1
    prep_w_kernel<<<(16384 + 255) / 256, 256, 0, stream>>>(Win, Wth, Wtl, 16384);
    prep_w_kernel<<<(4 * 16384 + 255) / 256, 256, 0, stream>>>(Wroot, Wth + 1 * 16384, Wtl + 1 * 16384, 4 * 16384);
    prep_w_kernel<<<(8 * 16384 + 255) / 256, 256, 0, stream>>>(Wrel, Wth + 5 * 16384, Wtl + 5 * 16384, 8 * 16384);
    prep_w_kernel<<<(16384 + 255) / 256, 256, 0, stream>>>(Wo1, Wth + 13 * 16384, Wtl + 13 * 16384, 16384);

    // encoder -> x
    enc_big_kernel<<<(N + BN - 1) / BN, 256, 0, stream>>>(
        des, tweet, Wd, bd, Wt, bt, x, N);
    enc_small_kernel<<<(N + 3) / 4, 256, 0, stream>>>(
        nump, catp, nf, Wn, bn, Wc, bc, Ww, bw, x, N);

    // CSR build
    count_kernel<<<(E + 255) / 256, 256, 0, stream>>>(ei, et, deg, E, N);
    scan1_kernel<<<nb, 256, 0, stream>>>(deg, bsum, m);
    scan2_kernel<<<1, 1024, 0, stream>>>(bsum, nb);
    scan3_kernel<<<nb, 256, 0, stream>>>(deg, bsum, offs, m);
    fill_kernel<<<(E + 255) / 256, 256, 0, stream>>>(ei, et, offs, ord, E, N);

    int nblk = (N + 63) / 64;   // 1563
    // x = lrelu(x @ W_in + b_in)
    dense_mfma_kernel<<<nblk, 256, 0, stream>>>(
        x, x, x, 128, 0, 128, 0, 128, 0, Wth, Wtl, 0, 0, 0, bin, x, 1, 1, N);

    for (int i = 0; i < 4; i++) {
        gather2_kernel<<<(N + 7) / 8, 256, 0, stream>>>(x, offs, ord, G, N);
        // x = x@Wroot[i] + G0@Wrel[i][0] + G1@Wrel[i][1] + b
        dense_mfma_kernel<<<nblk, 256, 0, stream>>>(
            x, G, G, 128, 0, 256, 0, 256, 128,
            Wth, Wtl, 1 + i, 5 + 2 * i, 6 + 2 * i,
            brg + (size_t)i * 128, x, 3, 0, N);
    }

    // x = lrelu(x @ W_o1 + b_o1)
    dense_mfma_kernel<<<nblk, 256, 0, stream>>>(
        x, x, x, 128, 0, 128, 0, 128, 0, Wth, Wtl, 13, 13, 13, bo1, x, 1, 1, N);
    head_kernel<<<(N + 3) / 4, 256, 0, stream>>>(x, Wo2, bo2, (float*)d_out, N);
}